// Round 1
// baseline (992.760 us; speedup 1.0000x reference)
//
#include <hip/hip_runtime.h>
#include <stdint.h>

#define K_SEL 512
#define NBOX 1536          // 3 * K_SEL
#define NWORDS 24          // NBOX / 64
#define CAND_CAP 4096
#define NBINS 65536

// scale params
#define M0 32448           // 64*13*13*3
#define M1 129792          // 64*26*26*3
#define M2 519168          // 64*52*52*3
#define M_TOT (M0+M1+M2)   // 681408

// ws byte offsets (all 16-aligned)
#define OFF_HIST 0u           // 3*65536*4 = 786432
#define OFF_CNT  786432u      // 3*4
#define OFF_THR  786448u      // 3*4
#define OFF_CAND 786464u      // 3*4096*8 = 98304
#define OFF_TOPK 884768u      // 1536*8
#define OFF_BOX  897056u      // 1536*7*4
#define OFF_SKEY 940064u      // 1536*8
#define OFF_SBOX 952352u      // 1536*7*4
#define OFF_GEOM 995360u      // 5*1536*4
#define OFF_VALW 1026080u     // 24*8
#define OFF_MASK 1026272u     // 1536*24*8 = 294912
#define OFF_SUPP 1321184u     // 24*8

typedef unsigned long long u64;
typedef uint32_t u32;

__device__ __forceinline__ float sigf(float x) { return 1.0f / (1.0f + expf(-x)); }

__device__ __forceinline__ u32 fmono(float f) {
    u32 u = __float_as_uint(f);
    return (u & 0x80000000u) ? ~u : (u | 0x80000000u);
}

__device__ __forceinline__ u64 shfl64(u64 v, int lane) {
    int lo = __shfl((int)(u32)(v & 0xffffffffull), lane);
    int hi = __shfl((int)(u32)(v >> 32), lane);
    return ((u64)(u32)hi << 32) | (u32)lo;
}

// map flat thread t over all scales -> (s, c, H)
__device__ __forceinline__ void scale_of(int t, int& s, int& c, int& H) {
    if (t < M0)            { s = 0; c = t;           H = 13; }
    else if (t < M0 + M1)  { s = 1; c = t - M0;      H = 26; }
    else                   { s = 2; c = t - M0 - M1; H = 52; }
}

__device__ __forceinline__ float conf_logit(const float* p, int c, int H) {
    int HW = H * H;
    int hw3 = HW * 3;
    int n = c / hw3; int rem = c - n * hw3;
    int pix = rem / 3; int a = rem - pix * 3;
    return p[(size_t)(n * 255 + a * 85) * HW + pix];
}

// ---------------- kernel 1: zero scratch ----------------
__global__ void k_zero(uint8_t* ws) {
    u32* hist = (u32*)(ws + OFF_HIST);
    int t = blockIdx.x * blockDim.x + threadIdx.x;
    if (t < 3 * NBINS) hist[t] = 0;
    if (t < 3) ((u32*)(ws + OFF_CNT))[t] = 0;
    if (t < NWORDS) {
        ((u64*)(ws + OFF_VALW))[t] = 0ull;
        ((u64*)(ws + OFF_SUPP))[t] = 0ull;
    }
}

// ---------------- kernel 2: conf histogram (top-16 bits of monotone key) ----------------
__global__ void k_hist(const float* p0, const float* p1, const float* p2, uint8_t* ws) {
    int t = blockIdx.x * blockDim.x + threadIdx.x;
    if (t >= M_TOT) return;
    int s, c, H; scale_of(t, s, c, H);
    const float* p = (s == 0) ? p0 : (s == 1) ? p1 : p2;
    float conf = sigf(conf_logit(p, c, H));
    u32 cb = fmono(conf);
    atomicAdd(&((u32*)(ws + OFF_HIST))[s * NBINS + (cb >> 16)], 1u);
}

// ---------------- kernel 3: find 16-bit threshold bin per scale ----------------
__global__ __launch_bounds__(1024) void k_scan(uint8_t* ws) {
    int s = blockIdx.x;
    u32* hist = (u32*)(ws + OFF_HIST) + s * NBINS;
    __shared__ u32 sum[1024];
    int t = threadIdx.x;
    u32 acc = 0;
    for (int b = t * 64; b < t * 64 + 64; ++b) acc += hist[b];
    sum[t] = acc;
    __syncthreads();
    // inclusive suffix scan over thread partials
    for (int off = 1; off < 1024; off <<= 1) {
        u32 v = (t + off < 1024) ? sum[t + off] : 0;
        __syncthreads();
        sum[t] += v;
        __syncthreads();
    }
    u32 excl = (t < 1023) ? sum[t + 1] : 0;       // count in bins above my range
    u32 mine = sum[t] - excl;
    if (excl < K_SEL && excl + mine >= K_SEL) {
        u32 cum = excl; int thr = t * 64;
        for (int b = t * 64 + 63; b >= t * 64; --b) {
            cum += hist[b];
            if (cum >= K_SEL) { thr = b; break; }
        }
        ((u32*)(ws + OFF_THR))[s] = (u32)thr;
    }
}

// ---------------- kernel 4: compact candidates >= threshold bin ----------------
__global__ void k_compact(const float* p0, const float* p1, const float* p2, uint8_t* ws) {
    int t = blockIdx.x * blockDim.x + threadIdx.x;
    if (t >= M_TOT) return;
    int s, c, H; scale_of(t, s, c, H);
    const float* p = (s == 0) ? p0 : (s == 1) ? p1 : p2;
    float conf = sigf(conf_logit(p, c, H));
    u32 cb = fmono(conf);
    if ((cb >> 16) >= ((u32*)(ws + OFF_THR))[s]) {
        u32 pos = atomicAdd(&((u32*)(ws + OFF_CNT))[s], 1u);
        if (pos < CAND_CAP) {
            u64 key = ((u64)cb << 32) | (u32)(~(u32)c);  // ties: smaller c ranks higher
            ((u64*)(ws + OFF_CAND))[s * CAND_CAP + pos] = key;
        }
    }
}

// ---------------- kernel 5: per-scale bitonic sort of candidates, emit top-512 ----------------
__global__ __launch_bounds__(1024) void k_sort3(uint8_t* ws) {
    int s = blockIdx.x;
    __shared__ u64 a[CAND_CAP];
    u32 cnt = ((u32*)(ws + OFF_CNT))[s];
    if (cnt > CAND_CAP) cnt = CAND_CAP;
    u64* cand = (u64*)(ws + OFF_CAND) + s * CAND_CAP;
    for (int i = threadIdx.x; i < CAND_CAP; i += 1024) a[i] = (i < (int)cnt) ? cand[i] : 0ull;
    __syncthreads();
    for (int k = 2; k <= CAND_CAP; k <<= 1) {
        for (int j = k >> 1; j > 0; j >>= 1) {
            for (int i = threadIdx.x; i < CAND_CAP; i += 1024) {
                int ixj = i ^ j;
                if (ixj > i) {
                    bool desc = ((i & k) == 0);
                    u64 x = a[i], y = a[ixj];
                    if (desc ? (x < y) : (x > y)) { a[i] = y; a[ixj] = x; }
                }
            }
            __syncthreads();
        }
    }
    u64* topk = (u64*)(ws + OFF_TOPK) + s * K_SEL;
    for (int r = threadIdx.x; r < K_SEL; r += 1024) topk[r] = a[r];
}

// ---------------- kernel 6: decode 1536 boxes + NMS sort keys ----------------
__global__ void k_decode(const float* p0, const float* p1, const float* p2,
                         const float* a0, const float* a1, const float* a2, uint8_t* ws) {
    int t = blockIdx.x * 256 + threadIdx.x;
    if (t >= NBOX) return;
    int s = t / K_SEL;
    int H = (s == 0) ? 13 : (s == 1) ? 26 : 52;
    float stride = (s == 0) ? 32.f : (s == 1) ? 16.f : 8.f;
    const float* p = (s == 0) ? p0 : (s == 1) ? p1 : p2;
    const float* anch = (s == 0) ? a0 : (s == 1) ? a1 : a2;
    int HW = H * H, hw3 = HW * 3;
    u64 key = ((u64*)(ws + OFF_TOPK))[t];
    int c = (int)(~(u32)key);
    int n = c / hw3; int rem = c - n * hw3;
    int pix = rem / 3; int a = rem - pix * 3;
    int h = pix / H, w = pix - h * H;
    size_t base = (size_t)(n * 255 + a * 85) * HW + pix;
    float v0 = p[base];
    float v1 = p[base + HW];
    float v2 = p[base + 2 * (size_t)HW];
    float v3 = p[base + 3 * (size_t)HW];
    float v4 = p[base + 4 * (size_t)HW];
    float conf = sigf(v0);
    float cx = ((float)w + sigf(v1)) * stride;
    float cy = ((float)h + sigf(v2)) * stride;
    float bw = anch[a * 2 + 0] * expf(v3);
    float bh = anch[a * 2 + 1] * expf(v4);
    float best = -INFINITY; int bi = 0;
    for (int k2 = 0; k2 < 80; ++k2) {
        float vv = p[base + (size_t)(5 + k2) * HW];
        if (vv > best) { best = vv; bi = k2; }   // first-occurrence argmax
    }
    float* box = (float*)(ws + OFF_BOX) + t * 7;
    box[0] = (float)n; box[1] = conf; box[2] = cx; box[3] = cy;
    box[4] = bw; box[5] = bh; box[6] = (float)bi;
    bool valid = conf > 0.5f;
    u32 mono = valid ? fmono(conf) : fmono(-INFINITY);
    ((u64*)(ws + OFF_SKEY))[t] = ((u64)mono << 32) | (u32)(~(u32)t);  // ties: smaller pos first
}

// ---------------- kernel 7: sort 1536 by score (stable), build sorted arrays ----------------
__global__ __launch_bounds__(1024) void k_sortnms(uint8_t* ws) {
    __shared__ u64 a[2048];
    int t = threadIdx.x;
    u64* skey = (u64*)(ws + OFF_SKEY);
    for (int i = t; i < 2048; i += 1024) a[i] = (i < NBOX) ? skey[i] : 0ull;
    __syncthreads();
    for (int k = 2; k <= 2048; k <<= 1) {
        for (int j = k >> 1; j > 0; j >>= 1) {
            for (int i = t; i < 2048; i += 1024) {
                int ixj = i ^ j;
                if (ixj > i) {
                    bool desc = ((i & k) == 0);
                    u64 x = a[i], y = a[ixj];
                    if (desc ? (x < y) : (x > y)) { a[i] = y; a[ixj] = x; }
                }
            }
            __syncthreads();
        }
    }
    float* box  = (float*)(ws + OFF_BOX);
    float* sbox = (float*)(ws + OFF_SBOX);
    float* geom = (float*)(ws + OFF_GEOM);
    for (int i = t; i < NBOX; i += 1024) {
        int pos = (int)(~(u32)a[i]);
        float b0 = box[pos * 7 + 0], b1 = box[pos * 7 + 1], b2 = box[pos * 7 + 2];
        float b3 = box[pos * 7 + 3], b4 = box[pos * 7 + 4], b5 = box[pos * 7 + 5];
        float b6 = box[pos * 7 + 6];
        sbox[i * 7 + 0] = b0; sbox[i * 7 + 1] = b1; sbox[i * 7 + 2] = b2;
        sbox[i * 7 + 3] = b3; sbox[i * 7 + 4] = b4; sbox[i * 7 + 5] = b5;
        sbox[i * 7 + 6] = b6;
        geom[i]            = b2 - b4 * 0.5f;   // x1
        geom[NBOX + i]     = b3 - b5 * 0.5f;   // y1
        geom[2 * NBOX + i] = b2 + b4 * 0.5f;   // x2
        geom[3 * NBOX + i] = b3 + b5 * 0.5f;   // y2
        geom[4 * NBOX + i] = b4 * b5;          // area
    }
    __syncthreads();
    if (t < NWORDS) {   // pack sorted valid mask
        u64 bits = 0;
        for (int b = 0; b < 64; ++b)
            if (sbox[(t * 64 + b) * 7 + 1] > 0.5f) bits |= 1ull << b;
        ((u64*)(ws + OFF_VALW))[t] = bits;
    }
}

// ---------------- kernel 8: IoU overlap bitmask (j > i, same image+class, iou > 0.1) ----------------
__global__ __launch_bounds__(256) void k_iou(uint8_t* ws) {
    __shared__ float sx1[NBOX], sy1[NBOX], sx2[NBOX], sy2[NBOX], sar[NBOX], snc[NBOX];
    float* geom = (float*)(ws + OFF_GEOM);
    float* sbox = (float*)(ws + OFF_SBOX);
    for (int i = threadIdx.x; i < NBOX; i += 256) {
        sx1[i] = geom[i];
        sy1[i] = geom[NBOX + i];
        sx2[i] = geom[2 * NBOX + i];
        sy2[i] = geom[3 * NBOX + i];
        sar[i] = geom[4 * NBOX + i];
        snc[i] = sbox[i * 7 + 0] * 128.f + sbox[i * 7 + 6];  // (n, cls) fused, exact
    }
    __syncthreads();
    int g = blockIdx.x * 256 + threadIdx.x;  // 0 .. 1536*24-1
    int i = g / NWORDS, w = g - i * NWORDS;
    float x1 = sx1[i], y1 = sy1[i], x2 = sx2[i], y2 = sy2[i], ar = sar[i], nc = snc[i];
    u64 bits = 0;
    int j0 = w * 64;
    for (int b = 0; b < 64; ++b) {
        int j = j0 + b;
        if (j <= i) continue;
        if (snc[j] != nc) continue;
        float ix1 = fmaxf(x1, sx1[j]), iy1 = fmaxf(y1, sy1[j]);
        float ix2 = fminf(x2, sx2[j]), iy2 = fminf(y2, sy2[j]);
        float iw = fmaxf(ix2 - ix1, 0.f), ih = fmaxf(iy2 - iy1, 0.f);
        float inter = iw * ih;
        float iou = inter / (ar + sar[j] - inter + 1e-9f);
        if (iou > 0.1f) bits |= 1ull << b;
    }
    ((u64*)(ws + OFF_MASK))[(size_t)i * NWORDS + w] = bits;
}

// ---------------- kernel 9: serial greedy NMS scan (one wave) ----------------
__global__ __launch_bounds__(64) void k_serial(uint8_t* ws) {
    int lane = threadIdx.x;
    u64* mask  = (u64*)(ws + OFF_MASK);
    u64 vw = (lane < NWORDS) ? ((u64*)(ws + OFF_VALW))[lane] : 0ull;
    u64 supp = 0;
    const int PF = 16;
    u64 buf[PF];
#pragma unroll
    for (int k = 0; k < PF; ++k)
        buf[k] = (lane < NWORDS) ? mask[(size_t)k * NWORDS + lane] : 0ull;
    for (int i0 = 0; i0 < NBOX; i0 += PF) {
#pragma unroll
        for (int k = 0; k < PF; ++k) {
            int i = i0 + k;
            int wsel = i >> 6, bi = i & 63;
            u64 sb = shfl64(supp, wsel);
            u64 vb = shfl64(vw, wsel);
            bool active = (((sb >> bi) & 1ull) == 0) && (((vb >> bi) & 1ull) != 0);
            u64 row = buf[k];
            if (i + PF < NBOX && lane < NWORDS)
                buf[k] = mask[(size_t)(i + PF) * NWORDS + lane];
            if (active) supp |= row;
        }
    }
    if (lane < NWORDS) ((u64*)(ws + OFF_SUPP))[lane] = supp;
}

// ---------------- kernel 10: write outputs ----------------
__global__ void k_out(uint8_t* ws, float* out) {
    int i = blockIdx.x * 256 + threadIdx.x;
    if (i >= NBOX) return;
    u64 vw = ((u64*)(ws + OFF_VALW))[i >> 6];
    u64 sw = ((u64*)(ws + OFF_SUPP))[i >> 6];
    int b = i & 63;
    float kf = (((vw >> b) & 1ull) && !((sw >> b) & 1ull)) ? 1.f : 0.f;
    float* sbox = (float*)(ws + OFF_SBOX) + i * 7;
    float* o = out + i * 7;
    for (int k2 = 0; k2 < 7; ++k2) o[k2] = sbox[k2] * kf;
    out[NBOX * 7 + i] = kf;
}

extern "C" void kernel_launch(void* const* d_in, const int* in_sizes, int n_in,
                              void* d_out, int out_size, void* d_ws, size_t ws_size,
                              hipStream_t stream) {
    const float* p0 = (const float*)d_in[0];
    const float* p1 = (const float*)d_in[1];
    const float* p2 = (const float*)d_in[2];
    const float* a0 = (const float*)d_in[3];
    const float* a1 = (const float*)d_in[4];
    const float* a2 = (const float*)d_in[5];
    uint8_t* ws = (uint8_t*)d_ws;
    float* out = (float*)d_out;

    const int GB = (M_TOT + 255) / 256;  // 2662

    k_zero   <<<768, 256, 0, stream>>>(ws);
    k_hist   <<<GB, 256, 0, stream>>>(p0, p1, p2, ws);
    k_scan   <<<3, 1024, 0, stream>>>(ws);
    k_compact<<<GB, 256, 0, stream>>>(p0, p1, p2, ws);
    k_sort3  <<<3, 1024, 0, stream>>>(ws);
    k_decode <<<6, 256, 0, stream>>>(p0, p1, p2, a0, a1, a2, ws);
    k_sortnms<<<1, 1024, 0, stream>>>(ws);
    k_iou    <<<(NBOX * NWORDS) / 256, 256, 0, stream>>>(ws);
    k_serial <<<1, 64, 0, stream>>>(ws);
    k_out    <<<6, 256, 0, stream>>>(ws, out);
}